// Round 9
// baseline (842.601 us; speedup 1.0000x reference)
//
#include <hip/hip_runtime.h>
#include <cstddef>

#define S_ 32
#define NM1 127
#define D_ 256
#define F_ 516
#define TRI_ 8128
#define G_ 768
#define M_ (S_ * NM1)   // 4064

typedef __bf16 v8bf __attribute__((ext_vector_type(8)));
typedef float v4f __attribute__((ext_vector_type(4)));

__device__ __forceinline__ unsigned short f2bf(float f) {
    unsigned int u = __float_as_uint(f);
    unsigned int r = (u + 0x7FFFu + ((u >> 16) & 1u)) >> 16;
    return (unsigned short)r;
}

__device__ __forceinline__ void store4bf(unsigned short* p, float4 v) {
    ushort4 q;
    q.x = f2bf(v.x); q.y = f2bf(v.y); q.z = f2bf(v.z); q.w = f2bf(v.w);
    *(ushort4*)p = q;
}

__device__ __forceinline__ v8bf u4_to_v8bf(uint4 u) {
    union { uint4 u; v8bf v; } x; x.u = u; return x.v;
}

__device__ __forceinline__ float bflo(unsigned int u) { return __uint_as_float(u << 16); }
__device__ __forceinline__ float bfhi(unsigned int u) { return __uint_as_float(u & 0xffff0000u); }

// volatile uint4 load: compiler cannot rematerialize -> forces VGPR residency
__device__ __forceinline__ uint4 vload4(const unsigned int* p) {
    uint4 r;
    r.x = *(volatile const unsigned int*)(p + 0);
    r.y = *(volatile const unsigned int*)(p + 1);
    r.z = *(volatile const unsigned int*)(p + 2);
    r.w = *(volatile const unsigned int*)(p + 3);
    return r;
}

__device__ __forceinline__ float sigmoidf_(float x) { return 1.f / (1.f + __expf(-x)); }

__device__ __forceinline__ float fast_tanh(float x) {
    float ax = fabsf(x);
    float e = __expf(2.f * ax);
    float t = 1.f - 2.f / (e + 1.f);
    return copysignf(t, x);
}

// ---------------------------------------------------------------------------
// K2: fused weight prep + c0 MLP + out-zero (one launch, block ranges).
// ---------------------------------------------------------------------------
__device__ __forceinline__ void do_packfrag(const float* __restrict__ W,
                                            uint4* __restrict__ wbuf, int idx,
                                            int ntiles)
{
    if (idx >= ntiles * 8 * 64) return;
    int ct = idx >> 9;
    int rem = idx & 511;
    int kk = rem >> 6;
    int lane = rem & 63;
    int lr = lane & 15, quad = lane >> 4;
    const float* src = W + (size_t)(ct * 16 + lr) * 256 + kk * 32 + quad * 8;
    unsigned int wd[4];
#pragma unroll
    for (int i = 0; i < 4; ++i)
        wd[i] = (unsigned int)f2bf(src[2 * i]) | ((unsigned int)f2bf(src[2 * i + 1]) << 16);
    uint4 v; v.x = wd[0]; v.y = wd[1]; v.z = wd[2]; v.w = wd[3];
    wbuf[idx] = v;
}

__device__ __forceinline__ void do_cvt(const float* __restrict__ src,
                                       unsigned short* __restrict__ dst,
                                       int idx, int N, int K, int lds_, int off, int ldd)
{
    if (idx >= N * ldd) return;
    int n = idx / ldd, k = idx - n * ldd;
    float v = (k < K) ? src[(size_t)n * lds_ + off + k] : 0.f;
    dst[idx] = f2bf(v);
}

// c0 MLP with 256 threads (single block)
__device__ void do_c0(const float* __restrict__ z_ph, const float* __restrict__ init_ph,
                      const float* __restrict__ W0, const float* __restrict__ b0,
                      const float* __restrict__ W1, const float* __restrict__ b1,
                      const float* __restrict__ W2, const float* __restrict__ b2,
                      float* __restrict__ c0_out, float* __restrict__ out_zero, int tid)
{
    __shared__ float v[512];
    __shared__ float h0[256];
    __shared__ float h1[128];
    if (tid < 64) out_zero[tid] = 0.f;
    v[tid] = z_ph[tid];
    v[256 + tid] = init_ph[tid];
    __syncthreads();
    {
        const float* w = W0 + (size_t)tid * 512;
        float a = b0[tid];
        for (int k = 0; k < 512; k += 4) {
            const float4 wv = *(const float4*)&w[k];
            const float4 vv = *(const float4*)&v[k];
            a += wv.x * vv.x + wv.y * vv.y + wv.z * vv.z + wv.w * vv.w;
        }
        h0[tid] = fmaxf(a, 0.f);
    }
    __syncthreads();
    if (tid < 128) {
        const float* w = W1 + (size_t)tid * 256;
        float a = b1[tid];
        for (int k = 0; k < 256; k += 4) {
            const float4 wv = *(const float4*)&w[k];
            const float4 vv = *(const float4*)&h0[k];
            a += wv.x * vv.x + wv.y * vv.y + wv.z * vv.z + wv.w * vv.w;
        }
        h1[tid] = fmaxf(a, 0.f);
    }
    __syncthreads();
    {
        const float* w = W2 + (size_t)tid * 128;
        float a = b2[tid];
        for (int k = 0; k < 128; k += 4) {
            const float4 wv = *(const float4*)&w[k];
            const float4 vv = *(const float4*)&h1[k];
            a += wv.x * vv.x + wv.y * vv.y + wv.z * vv.z + wv.w * vv.w;
        }
        c0_out[tid] = a;
    }
}

// segments (blocks of 256): fragU 96 | fragD 96 | fragW1 16 | rw 520 |
// uw 768 | dw 768 | w0lo 256 | w0hi 256 | c0 1  => 2777
#define PREP_BLOCKS 2777

__global__ __launch_bounds__(256) void prep_all(
    const float* __restrict__ upd_Whh, uint4* __restrict__ wfU,
    const float* __restrict__ dec_Whh, uint4* __restrict__ wfD,
    const float* __restrict__ er_W1, uint4* __restrict__ w1f,
    const float* __restrict__ rr_W, unsigned short* __restrict__ rwbf,
    const float* __restrict__ upd_Wih, unsigned short* __restrict__ uwbf,
    const float* __restrict__ dec_Wih, unsigned short* __restrict__ dwbf,
    const float* __restrict__ er_W0, unsigned short* __restrict__ w0bf,
    const float* __restrict__ z_ph, const float* __restrict__ init_ph,
    const float* __restrict__ cc_W0, const float* __restrict__ cc_b0,
    const float* __restrict__ cc_W1, const float* __restrict__ cc_b1,
    const float* __restrict__ cc_W2, const float* __restrict__ cc_b2,
    float* __restrict__ c0_out, float* __restrict__ out_zero)
{
    int bid = blockIdx.x;
    const int tid = threadIdx.x;
    if (bid < 96) { do_packfrag(upd_Whh, wfU, bid * 256 + tid, 48); return; }
    bid -= 96;
    if (bid < 96) { do_packfrag(dec_Whh, wfD, bid * 256 + tid, 48); return; }
    bid -= 96;
    if (bid < 16) { do_packfrag(er_W1, w1f, bid * 256 + tid, 8); return; }
    bid -= 16;
    if (bid < 520) { do_cvt(rr_W, rwbf, bid * 256 + tid, 256, 516, 516, 0, 520); return; }
    bid -= 520;
    if (bid < 768) { do_cvt(upd_Wih, uwbf, bid * 256 + tid, 768, 256, 256, 0, 256); return; }
    bid -= 768;
    if (bid < 768) { do_cvt(dec_Wih, dwbf, bid * 256 + tid, 768, 256, 256, 0, 256); return; }
    bid -= 768;
    if (bid < 256) { do_cvt(er_W0, w0bf, bid * 256 + tid, 256, 256, 512, 0, 256); return; }
    bid -= 256;
    if (bid < 256) { do_cvt(er_W0, w0bf + 256 * 256, bid * 256 + tid, 256, 256, 512, 256, 256); return; }
    bid -= 256;
    do_c0(z_ph, init_ph, cc_W0, cc_b0, cc_W1, cc_b1, cc_W2, cc_b2,
          c0_out, out_zero, tid);
}

// ---------------------------------------------------------------------------
// K3: bf16 MFMA GEMM, 64x64 tile, K chunked by 128, XOR-swizzled LDS.
// split mode writes bf16 outputs (Amat/Bmat for the edge kernel).
// ---------------------------------------------------------------------------
__global__ __launch_bounds__(256) void gemm_mfma(
    const float* __restrict__ A, const unsigned short* __restrict__ B,
    const float* __restrict__ bias, const float* __restrict__ c0,
    float* __restrict__ C, float* __restrict__ C2,
    int M, int N, int K, int lda, int ldb, int mode, int act, int split)
{
    __shared__ __align__(16) unsigned short As[64 * 128];
    __shared__ __align__(16) unsigned short Bs[64 * 128];
    const int tid = threadIdx.x;
    const int m0 = blockIdx.x * 64, n0 = blockIdx.y * 64;
    const int wave = tid >> 6, lane = tid & 63;
    const int lr = lane & 15, quad = lane >> 4;

    v4f acc[4];
    const v4f z4 = {0.f, 0.f, 0.f, 0.f};
#pragma unroll
    for (int nt = 0; nt < 4; ++nt) acc[nt] = z4;

    for (int k0 = 0; k0 < K; k0 += 128) {
        for (int idx = tid; idx < 64 * 32; idx += 256) {
            int r = idx >> 5, kq = idx & 31;
            int k = k0 + kq * 4;
            int m = m0 + r; if (m > M - 1) m = M - 1;
            float4 a = {0.f, 0.f, 0.f, 0.f};
            if (k < K) {
                const float* Ar;
                if (mode == 1) {
                    int ss = m / 127, tt = m - ss * 127;
                    Ar = A + (size_t)(ss * 128 + tt + 1) * lda;
                } else if (mode == 2) {
                    int tt = m % 127;
                    Ar = (tt == 0) ? c0 : (A + (size_t)(m - 1) * lda);
                } else {
                    Ar = A + (size_t)m * lda;
                }
                a = *(const float4*)&Ar[k];
            }
            store4bf(&As[r * 128 + (((kq >> 1) ^ (r & 7)) << 3) + ((kq & 1) << 2)], a);
        }
        for (int idx = tid; idx < 64 * 16; idx += 256) {
            int c = idx >> 4, kb = idx & 15;
            int k = k0 + kb * 8;
            int n = n0 + c;
            uint4 bv = {0u, 0u, 0u, 0u};
            if (k < K) bv = *(const uint4*)&B[(size_t)n * ldb + k];
            *(uint4*)&Bs[c * 128 + ((kb ^ (c & 7)) << 3)] = bv;
        }
        __syncthreads();
        const int row = wave * 16 + lr;
        const int rem = K - k0;
        const int kkm = (rem >= 128) ? 4 : ((rem + 31) >> 5);
        for (int kk = 0; kk < kkm; ++kk) {
            const v8bf af = *(const v8bf*)&As[row * 128 + ((((kk << 2) + quad) ^ (row & 7)) << 3)];
#pragma unroll
            for (int nt = 0; nt < 4; ++nt) {
                const int col = nt * 16 + lr;
                const v8bf bf = *(const v8bf*)&Bs[col * 128 + ((((kk << 2) + quad) ^ (col & 7)) << 3)];
                acc[nt] = __builtin_amdgcn_mfma_f32_16x16x32_bf16(af, bf, acc[nt], 0, 0, 0);
            }
        }
        __syncthreads();
    }
#pragma unroll
    for (int nt = 0; nt < 4; ++nt) {
        const int col = n0 + nt * 16 + lr;
#pragma unroll
        for (int r = 0; r < 4; ++r) {
            const int row = m0 + wave * 16 + quad * 4 + r;
            if (row < M) {
                float v = acc[nt][r];
                if (split) {
                    if (col < 256)
                        ((unsigned short*)C)[(size_t)row * 256 + col] = f2bf(v);
                    else
                        ((unsigned short*)C2)[(size_t)row * 256 + (col - 256)] =
                            f2bf(v + bias[col - 256]);
                } else {
                    if (bias) v += bias[col];
                    if (act) v = fmaxf(v, 0.f);
                    C[(size_t)row * N + col] = v;
                }
            }
        }
    }
}

// ---------------------------------------------------------------------------
// K4: GRU scan v8 — MFMA matvec, gru_scan6 structure + VOLATILE-held tiles.
// 512 thr/sample, wave w owns col-tiles 6w..6w+5. ct0-2 loaded pre-loop via
// volatile loads (unrematerializable -> allocator must keep in VGPRs, ~96),
// ct3-5 streamed per step (192 KB/block/step vs 384 in v6; L2 ~131 B/cyc/CU).
// A-fragments loaded once per step and reused across all 6 tiles.
// ---------------------------------------------------------------------------
__global__ __launch_bounds__(512, 1) void gru_scan8(
    const float* __restrict__ gi, const uint4* __restrict__ wf,
    const float* __restrict__ bhh, float* __restrict__ outp, int T)
{
    const int s = blockIdx.x, tid = threadIdx.x;
    const int w = tid >> 6, lane = tid & 63;
    const int quad = lane >> 4;
    __shared__ unsigned int hbuf[2][128];
    __shared__ float dred[768];

    // held B-fragments: col-tiles 6w..6w+2 (volatile -> VGPR-resident)
    uint4 wh[3][8];
#pragma unroll
    for (int c = 0; c < 3; ++c)
#pragma unroll
        for (int kk = 0; kk < 8; ++kk)
            wh[c][kk] = vload4((const unsigned int*)(wf + (((((w * 6 + c) * 8) + kk) << 6) | lane)));

    const uint4* wp3 = wf + ((((w * 6 + 3) * 8) << 6) | lane);
    const uint4* wp4 = wf + ((((w * 6 + 4) * 8) << 6) | lane);
    const uint4* wp5 = wf + ((((w * 6 + 5) * 8) << 6) | lane);

    float br = 0.f, bz = 0.f, bn = 0.f;
    float g_r = 0.f, g_z = 0.f, g_n = 0.f;
    const float* g0 = gi + (size_t)s * T * G_;
    float* o0 = outp + (size_t)s * T * D_;
    float h = 0.f;
    if (tid < 256) {
        br = bhh[tid]; bz = bhh[256 + tid]; bn = bhh[512 + tid];
        g_r = g0[tid]; g_z = g0[256 + tid]; g_n = g0[512 + tid];
    }
    if (tid < 128) { hbuf[0][tid] = 0u; hbuf[1][tid] = 0u; }

    v4f acc[6];
    const v4f z4 = {0.f, 0.f, 0.f, 0.f};
#pragma unroll
    for (int c = 0; c < 6; ++c) acc[c] = z4;
    __syncthreads();

    for (int t = 0; t < T; ++t) {
        float ngr = 0.f, ngz = 0.f, ngn = 0.f;
        if (tid < 256 && t + 1 < T) {
            const float* gn_ = g0 + (size_t)(t + 1) * G_;
            ngr = gn_[tid]; ngz = gn_[256 + tid]; ngn = gn_[512 + tid];
        }
        const unsigned int* hq = hbuf[t & 1];
        // A-fragments once per step (8 ds_read_b128/wave, reused 6x)
        v8bf af[8];
#pragma unroll
        for (int kk = 0; kk < 8; ++kk)
            af[kk] = *(const v8bf*)&hq[kk * 16 + quad * 4];
        // held tiles
#pragma unroll
        for (int kk = 0; kk < 8; ++kk) {
            acc[0] = __builtin_amdgcn_mfma_f32_16x16x32_bf16(af[kk], u4_to_v8bf(wh[0][kk]), acc[0], 0, 0, 0);
            acc[1] = __builtin_amdgcn_mfma_f32_16x16x32_bf16(af[kk], u4_to_v8bf(wh[1][kk]), acc[1], 0, 0, 0);
            acc[2] = __builtin_amdgcn_mfma_f32_16x16x32_bf16(af[kk], u4_to_v8bf(wh[2][kk]), acc[2], 0, 0, 0);
        }
        // streamed tiles (compiler pipelines the loads)
#pragma unroll
        for (int kk = 0; kk < 8; ++kk)
            acc[3] = __builtin_amdgcn_mfma_f32_16x16x32_bf16(af[kk], u4_to_v8bf(wp3[kk << 6]), acc[3], 0, 0, 0);
#pragma unroll
        for (int kk = 0; kk < 8; ++kk)
            acc[4] = __builtin_amdgcn_mfma_f32_16x16x32_bf16(af[kk], u4_to_v8bf(wp4[kk << 6]), acc[4], 0, 0, 0);
#pragma unroll
        for (int kk = 0; kk < 8; ++kk)
            acc[5] = __builtin_amdgcn_mfma_f32_16x16x32_bf16(af[kk], u4_to_v8bf(wp5[kk << 6]), acc[5], 0, 0, 0);

        // y extraction: D row 0 lives in lanes 0..15, reg 0
        if (lane < 16) {
#pragma unroll
            for (int c = 0; c < 6; ++c)
                dred[(w * 6 + c) * 16 + lane] = acc[c][0];
        }
#pragma unroll
        for (int c = 0; c < 6; ++c) acc[c] = z4;
        __syncthreads();
        if (tid < 256) {
            const float rg = sigmoidf_(g_r + dred[tid] + br);
            const float zg = sigmoidf_(g_z + dred[256 + tid] + bz);
            const float ng = fast_tanh(g_n + rg * (dred[512 + tid] + bn));
            const float hnew = ng + zg * (h - ng);
            h = hnew;
            o0[(size_t)t * D_ + tid] = hnew;
            const float ho = __shfl_xor(hnew, 1);
            if ((tid & 1) == 0)
                hbuf[(t + 1) & 1][tid >> 1] =
                    (unsigned int)f2bf(hnew) | ((unsigned int)f2bf(ho) << 16);
            g_r = ngr; g_z = ngz; g_n = ngn;
        }
        __syncthreads();
    }
}

// ---------------------------------------------------------------------------
// K5: edge readout v2 (unchanged).
// ---------------------------------------------------------------------------
__global__ __launch_bounds__(256, 3) void edge_kernel2(
    const unsigned short* __restrict__ Abf, const unsigned short* __restrict__ Bbf,
    const uint4* __restrict__ w1f, const float* __restrict__ b1,
    const float* __restrict__ W2, const float* __restrict__ b2,
    const float* __restrict__ con, float* __restrict__ out)
{
    __shared__ __align__(16) unsigned short h1s[64 * 256];
    __shared__ int ijs[128];
    __shared__ float part[4][64][2];
    const int tid = threadIdx.x;
    const int s = blockIdx.y;
    const int e0 = blockIdx.x * 64;
    const int wave = tid >> 6, lane = tid & 63;
    const int lr = lane & 15, quad = lane >> 4;

    uint4 wfr[2][8];
#pragma unroll
    for (int c = 0; c < 2; ++c)
#pragma unroll
        for (int kk = 0; kk < 8; ++kk)
            wfr[c][kk] = w1f[((((wave * 2 + c) * 8) + kk) << 6) | lane];

    const int ca = wave * 32 + lr, cb = wave * 32 + 16 + lr;
    const float b1a = b1[ca], b1b = b1[cb];
    const float w20a = W2[ca], w20b = W2[cb];
    const float w21a = W2[128 + ca], w21b = W2[128 + cb];
    const float cb20 = b2[0], cb21 = b2[1];

    if (tid < 64) {
        int e = e0 + tid;
        int i = (int)((sqrtf(8.f * (float)e + 1.f) - 1.f) * 0.5f);
        while (((i + 1) * (i + 2)) / 2 <= e) ++i;
        while ((i * (i + 1)) / 2 > e) --i;
        ijs[tid * 2] = i;
        ijs[tid * 2 + 1] = e - (i * (i + 1)) / 2;
    }
    __syncthreads();

    {
        const unsigned short* Aro = Abf + (size_t)s * NM1 * 256;
        const unsigned short* Bro = Bbf + (size_t)s * NM1 * 256;
#pragma unroll
        for (int it = 0; it < 8; ++it) {
            int idx = tid + it * 256;
            int e = idx >> 5, k8 = idx & 31;
            int i = ijs[2 * e], j = ijs[2 * e + 1];
            uint4 av = *(const uint4*)&Aro[(size_t)j * 256 + k8 * 8];
            uint4 bv = *(const uint4*)&Bro[(size_t)i * 256 + k8 * 8];
            unsigned int rr[4];
#pragma unroll
            for (int wd = 0; wd < 4; ++wd) {
                unsigned int aw = (&av.x)[wd], bw = (&bv.x)[wd];
                float lo = fmaxf(bflo(aw) + bflo(bw), 0.f);
                float hi = fmaxf(bfhi(aw) + bfhi(bw), 0.f);
                rr[wd] = (unsigned int)f2bf(lo) | ((unsigned int)f2bf(hi) << 16);
            }
            uint4 hv; hv.x = rr[0]; hv.y = rr[1]; hv.z = rr[2]; hv.w = rr[3];
            *(uint4*)&h1s[e * 256 + ((k8 ^ (e & 7)) << 3)] = hv;
        }
    }
    __syncthreads();

    v4f acc[4][2];
    const v4f z4 = {0.f, 0.f, 0.f, 0.f};
#pragma unroll
    for (int rt = 0; rt < 4; ++rt) { acc[rt][0] = z4; acc[rt][1] = z4; }

#pragma unroll
    for (int kk = 0; kk < 8; ++kk) {
        v8bf af[4];
#pragma unroll
        for (int rt = 0; rt < 4; ++rt) {
            const int row = rt * 16 + lr;
            af[rt] = *(const v8bf*)&h1s[row * 256 + ((((kk << 2) + quad) ^ (row & 7)) << 3)];
        }
#pragma unroll
        for (int rt = 0; rt < 4; ++rt) {
            acc[rt][0] = __builtin_amdgcn_mfma_f32_16x16x32_bf16(
                af[rt], u4_to_v8bf(wfr[0][kk]), acc[rt][0], 0, 0, 0);
            acc[rt][1] = __builtin_amdgcn_mfma_f32_16x16x32_bf16(
                af[rt], u4_to_v8bf(wfr[1][kk]), acc[rt][1], 0, 0, 0);
        }
    }

#pragma unroll
    for (int rt = 0; rt < 4; ++rt) {
#pragma unroll
        for (int r = 0; r < 4; ++r) {
            float h2a = fmaxf(acc[rt][0][r] + b1a, 0.f);
            float h2b = fmaxf(acc[rt][1][r] + b1b, 0.f);
            float p0 = h2a * w20a + h2b * w20b;
            float p1 = h2a * w21a + h2b * w21b;
#pragma unroll
            for (int d = 1; d < 16; d <<= 1) {
                p0 += __shfl_xor(p0, d);
                p1 += __shfl_xor(p1, d);
            }
            if (lr == 0) {
                int e = rt * 16 + quad * 4 + r;
                part[wave][e][0] = p0;
                part[wave][e][1] = p1;
            }
        }
    }
    __syncthreads();

    if (tid < 64) {
        float l0 = part[0][tid][0] + part[1][tid][0] + part[2][tid][0] + part[3][tid][0] + cb20;
        float l1 = part[0][tid][1] + part[1][tid][1] + part[2][tid][1] + part[3][tid][1] + cb21;
        int e = e0 + tid;
        float mx = fmaxf(l0, l1);
        float lse = mx + logf(__expf(l0 - mx) + __expf(l1 - mx));
        float lp0 = fmaxf(l0 - lse, -100.f);
        float lp1 = fmaxf(l1 - lse, -100.f);
        float c0v = con[((size_t)s * TRI_ + e) * 2];
        float c1v = con[((size_t)s * TRI_ + e) * 2 + 1];
        float bsum0 = -(c0v * lp0 + (1.f - c0v) * lp1);
        float bsum1 = -(c1v * lp1 + (1.f - c1v) * lp0);
#pragma unroll
        for (int d = 1; d < 64; d <<= 1) {
            bsum0 += __shfl_xor(bsum0, d);
            bsum1 += __shfl_xor(bsum1, d);
        }
        if (tid == 0) {
            atomicAdd(&out[s * 2], bsum0);
            atomicAdd(&out[s * 2 + 1], bsum1);
        }
    }
}

// ---------------------------------------------------------------------------
extern "C" void kernel_launch(void* const* d_in, const int* in_sizes, int n_in,
                              void* d_out, int out_size, void* d_ws, size_t ws_size,
                              hipStream_t stream)
{
    (void)in_sizes; (void)n_in; (void)out_size; (void)ws_size;
    const float* x        = (const float*)d_in[0];
    const float* con      = (const float*)d_in[1];
    const float* z_ph     = (const float*)d_in[2];
    const float* init_ph  = (const float*)d_in[3];
    const float* cc_W0    = (const float*)d_in[4];
    const float* cc_b0    = (const float*)d_in[5];
    const float* cc_W1    = (const float*)d_in[6];
    const float* cc_b1    = (const float*)d_in[7];
    const float* cc_W2    = (const float*)d_in[8];
    const float* cc_b2    = (const float*)d_in[9];
    const float* er_W0    = (const float*)d_in[10];
    const float* er_b0    = (const float*)d_in[11];
    const float* er_W1    = (const float*)d_in[12];
    const float* er_b1    = (const float*)d_in[13];
    const float* er_W2    = (const float*)d_in[14];
    const float* er_b2    = (const float*)d_in[15];
    const float* rr_W     = (const float*)d_in[16];
    const float* rr_b     = (const float*)d_in[17];
    const float* dec_Wih  = (const float*)d_in[18];
    const float* dec_Whh  = (const float*)d_in[19];
    const float* dec_bih  = (const float*)d_in[20];
    const float* dec_bhh  = (const float*)d_in[21];
    const float* upd_Wih  = (const float*)d_in[22];
    const float* upd_Whh  = (const float*)d_in[23];
    const float* upd_bih  = (const float*)d_in[24];
    const float* upd_bhh  = (const float*)d_in[25];
    float* out = (float*)d_out;

    float* ws = (float*)d_ws;
    float* c0v  = ws;                               // 256
    float* gi   = ws + 256;                         // M_*G_
    float* bufA = gi + (size_t)M_ * G_;             // M_*D_ (rnninp fp32, Amat bf16)
    float* bufB = bufA + (size_t)M_ * D_;           // M_*D_ (u_out fp32, Bmat bf16)
    float* memb = bufB + (size_t)M_ * D_;           // M_*D_ (mem fp32)
    unsigned short* rwbf = (unsigned short*)(memb + (size_t)M_ * D_); // 256*520
    unsigned short* uwbf = rwbf + 256 * 520;                          // 768*256
    unsigned short* dwbf = uwbf + 768 * 256;                          // 768*256
    unsigned short* w0bf = dwbf + 768 * 256;                          // 512*256
    uint4* wfU = (uint4*)(((size_t)(w0bf + 512 * 256) + 15) & ~(size_t)15); // 24576
    uint4* wfD = wfU + 48 * 8 * 64;                                   // 24576
    uint4* w1f = wfD + 48 * 8 * 64;                                   // 4096

    // 1) fused weight prep + c0 + out-zero
    prep_all<<<PREP_BLOCKS, 256, 0, stream>>>(upd_Whh, wfU, dec_Whh, wfD,
                                              er_W1, w1f,
                                              rr_W, rwbf, upd_Wih, uwbf,
                                              dec_Wih, dwbf, er_W0, w0bf,
                                              z_ph, init_ph, cc_W0, cc_b0,
                                              cc_W1, cc_b1, cc_W2, cc_b2,
                                              c0v, out);
    // 2) rnninp = relu(x[:,1:] @ rr_W.T + rr_b)   -> bufA
    gemm_mfma<<<dim3((M_ + 63) / 64, 256 / 64), 256, 0, stream>>>(
        x, rwbf, rr_b, nullptr, bufA, nullptr, M_, 256, 516, 516, 520, 1, 1, 0);
    // 3) gi_u = rnninp @ upd_Wih.T + upd_bih      -> gi
    gemm_mfma<<<dim3((M_ + 63) / 64, 768 / 64), 256, 0, stream>>>(
        bufA, uwbf, upd_bih, nullptr, gi, nullptr, M_, 768, 256, 256, 256, 0, 0, 0);
    // 4) u_out = GRU(gi_u; upd)                   -> bufB
    gru_scan8<<<S_, 512, 0, stream>>>(gi, wfU, upd_bhh, bufB, NM1);
    // 5) gi_d = content_seq @ dec_Wih.T + dec_bih -> gi
    gemm_mfma<<<dim3((M_ + 63) / 64, 768 / 64), 256, 0, stream>>>(
        bufB, dwbf, dec_bih, c0v, gi, nullptr, M_, 768, 256, 256, 256, 2, 0, 0);
    // 6) mem = GRU(gi_d; dec)                     -> memb
    gru_scan8<<<S_, 512, 0, stream>>>(gi, wfD, dec_bhh, memb, NM1);
    // 7+8) Amat / Bmat = mem @ er_W0 halves (split N=512, bf16 out)
    gemm_mfma<<<dim3((M_ + 63) / 64, 512 / 64), 256, 0, stream>>>(
        memb, w0bf, er_b0, nullptr, bufA, bufB, M_, 512, 256, 256, 256, 0, 0, 1);
    // 9) fused edge readout -> out (atomicAdd)
    edge_kernel2<<<dim3(TRI_ / 64, S_), 256, 0, stream>>>(
        (const unsigned short*)bufA, (const unsigned short*)bufB,
        w1f, er_b1, er_W2, er_b2, con, out);
}

// Round 10
// 653.275 us; speedup vs baseline: 1.2898x; 1.2898x over previous
//
#include <hip/hip_runtime.h>
#include <hip/hip_fp8.h>
#include <cstddef>

#define S_ 32
#define NM1 127
#define D_ 256
#define F_ 516
#define TRI_ 8128
#define G_ 768
#define M_ (S_ * NM1)   // 4064

typedef __bf16 v8bf __attribute__((ext_vector_type(8)));
typedef float v4f __attribute__((ext_vector_type(4)));

__device__ __forceinline__ unsigned short f2bf(float f) {
    unsigned int u = __float_as_uint(f);
    unsigned int r = (u + 0x7FFFu + ((u >> 16) & 1u)) >> 16;
    return (unsigned short)r;
}

__device__ __forceinline__ void store4bf(unsigned short* p, float4 v) {
    ushort4 q;
    q.x = f2bf(v.x); q.y = f2bf(v.y); q.z = f2bf(v.z); q.w = f2bf(v.w);
    *(ushort4*)p = q;
}

__device__ __forceinline__ v8bf u4_to_v8bf(uint4 u) {
    union { uint4 u; v8bf v; } x; x.u = u; return x.v;
}

__device__ __forceinline__ float bflo(unsigned int u) { return __uint_as_float(u << 16); }
__device__ __forceinline__ float bfhi(unsigned int u) { return __uint_as_float(u & 0xffff0000u); }

__device__ __forceinline__ unsigned int f2fp8(float f) {
    __hip_fp8_e4m3 q(f);
    return (unsigned int)q.__x;
}

// fp8 MFMA: A = 8 fp8 (uint2), B = 8 fp8 (two dwords)
__device__ __forceinline__ v4f mfma_fp8(uint2 a, unsigned int bx, unsigned int by, v4f c) {
    union { uint2 u; long l; } ua, ub;
    ua.u = a; ub.u.x = bx; ub.u.y = by;
    return __builtin_amdgcn_mfma_f32_16x16x32_fp8_fp8(ua.l, ub.l, c, 0, 0, 0);
}

__device__ __forceinline__ float sigmoidf_(float x) { return 1.f / (1.f + __expf(-x)); }

__device__ __forceinline__ float fast_tanh(float x) {
    float ax = fabsf(x);
    float e = __expf(2.f * ax);
    float t = 1.f - 2.f / (e + 1.f);
    return copysignf(t, x);
}

// ---------------------------------------------------------------------------
// K2: fused weight prep + c0 MLP + out-zero (one launch, block ranges).
// packfrag (bf16 B-frags): wbuf[(ct*8+kk)*64+lane] = W[rowoff+ct*16+lr]
//                                                     [kk*32+quad*8 .. +7]
// packfp8 (fp8 B-frag PAIRS): wbuf[(ct*4+kp)*64+lane] = uint4 { frag 2kp (8B),
//                             frag 2kp+1 (8B) } of W rows ct*16.. (r,z block)
// ---------------------------------------------------------------------------
__device__ __forceinline__ void do_packfrag(const float* __restrict__ W,
                                            uint4* __restrict__ wbuf, int idx,
                                            int ntiles, int rowoff)
{
    if (idx >= ntiles * 8 * 64) return;
    int ct = idx >> 9;
    int rem = idx & 511;
    int kk = rem >> 6;
    int lane = rem & 63;
    int lr = lane & 15, quad = lane >> 4;
    const float* src = W + (size_t)(rowoff + ct * 16 + lr) * 256 + kk * 32 + quad * 8;
    unsigned int wd[4];
#pragma unroll
    for (int i = 0; i < 4; ++i)
        wd[i] = (unsigned int)f2bf(src[2 * i]) | ((unsigned int)f2bf(src[2 * i + 1]) << 16);
    uint4 v; v.x = wd[0]; v.y = wd[1]; v.z = wd[2]; v.w = wd[3];
    wbuf[idx] = v;
}

__device__ __forceinline__ void do_packfp8(const float* __restrict__ W,
                                           uint4* __restrict__ wbuf, int idx)
{
    if (idx >= 32 * 4 * 64) return;
    int ct = idx >> 8;          // 4*64 entries per tile
    int rem = idx & 255;
    int kp = rem >> 6, lane = rem & 63;
    int lr = lane & 15, quad = lane >> 4;
    unsigned int wd[4];
#pragma unroll
    for (int half = 0; half < 2; ++half) {
        const float* src = W + (size_t)(ct * 16 + lr) * 256 + (2 * kp + half) * 32 + quad * 8;
        unsigned int lo = 0, hi = 0;
#pragma unroll
        for (int i = 0; i < 4; ++i) lo |= f2fp8(src[i]) << (8 * i);
#pragma unroll
        for (int i = 0; i < 4; ++i) hi |= f2fp8(src[4 + i]) << (8 * i);
        wd[half * 2] = lo; wd[half * 2 + 1] = hi;
    }
    uint4 v; v.x = wd[0]; v.y = wd[1]; v.z = wd[2]; v.w = wd[3];
    wbuf[idx] = v;
}

__device__ __forceinline__ void do_cvt(const float* __restrict__ src,
                                       unsigned short* __restrict__ dst,
                                       int idx, int N, int K, int lds_, int off, int ldd)
{
    if (idx >= N * ldd) return;
    int n = idx / ldd, k = idx - n * ldd;
    float v = (k < K) ? src[(size_t)n * lds_ + off + k] : 0.f;
    dst[idx] = f2bf(v);
}

__device__ void do_c0(const float* __restrict__ z_ph, const float* __restrict__ init_ph,
                      const float* __restrict__ W0, const float* __restrict__ b0,
                      const float* __restrict__ W1, const float* __restrict__ b1,
                      const float* __restrict__ W2, const float* __restrict__ b2,
                      float* __restrict__ c0_out, float* __restrict__ out_zero, int tid)
{
    __shared__ float v[512];
    __shared__ float h0[256];
    __shared__ float h1[128];
    if (tid < 64) out_zero[tid] = 0.f;
    v[tid] = z_ph[tid];
    v[256 + tid] = init_ph[tid];
    __syncthreads();
    {
        const float* w = W0 + (size_t)tid * 512;
        float a = b0[tid];
        for (int k = 0; k < 512; k += 4) {
            const float4 wv = *(const float4*)&w[k];
            const float4 vv = *(const float4*)&v[k];
            a += wv.x * vv.x + wv.y * vv.y + wv.z * vv.z + wv.w * vv.w;
        }
        h0[tid] = fmaxf(a, 0.f);
    }
    __syncthreads();
    if (tid < 128) {
        const float* w = W1 + (size_t)tid * 256;
        float a = b1[tid];
        for (int k = 0; k < 256; k += 4) {
            const float4 wv = *(const float4*)&w[k];
            const float4 vv = *(const float4*)&h0[k];
            a += wv.x * vv.x + wv.y * vv.y + wv.z * vv.z + wv.w * vv.w;
        }
        h1[tid] = fmaxf(a, 0.f);
    }
    __syncthreads();
    {
        const float* w = W2 + (size_t)tid * 128;
        float a = b2[tid];
        for (int k = 0; k < 128; k += 4) {
            const float4 wv = *(const float4*)&w[k];
            const float4 vv = *(const float4*)&h1[k];
            a += wv.x * vv.x + wv.y * vv.y + wv.z * vv.z + wv.w * vv.w;
        }
        c0_out[tid] = a;
    }
}

// segments (blocks of 256): fragUn 32 | fragDn 32 | f8U 32 | f8D 32 |
// fragW1 16 | rw 520 | uw 768 | dw 768 | w0lo 256 | w0hi 256 | c0 1 => 2713
#define PREP_BLOCKS 2713

__global__ __launch_bounds__(256) void prep_all(
    const float* __restrict__ upd_Whh, uint4* __restrict__ wfnU, uint4* __restrict__ wf8U,
    const float* __restrict__ dec_Whh, uint4* __restrict__ wfnD, uint4* __restrict__ wf8D,
    const float* __restrict__ er_W1, uint4* __restrict__ w1f,
    const float* __restrict__ rr_W, unsigned short* __restrict__ rwbf,
    const float* __restrict__ upd_Wih, unsigned short* __restrict__ uwbf,
    const float* __restrict__ dec_Wih, unsigned short* __restrict__ dwbf,
    const float* __restrict__ er_W0, unsigned short* __restrict__ w0bf,
    const float* __restrict__ z_ph, const float* __restrict__ init_ph,
    const float* __restrict__ cc_W0, const float* __restrict__ cc_b0,
    const float* __restrict__ cc_W1, const float* __restrict__ cc_b1,
    const float* __restrict__ cc_W2, const float* __restrict__ cc_b2,
    float* __restrict__ c0_out, float* __restrict__ out_zero)
{
    int bid = blockIdx.x;
    const int tid = threadIdx.x;
    if (bid < 32) { do_packfrag(upd_Whh, wfnU, bid * 256 + tid, 16, 512); return; }
    bid -= 32;
    if (bid < 32) { do_packfrag(dec_Whh, wfnD, bid * 256 + tid, 16, 512); return; }
    bid -= 32;
    if (bid < 32) { do_packfp8(upd_Whh, wf8U, bid * 256 + tid); return; }
    bid -= 32;
    if (bid < 32) { do_packfp8(dec_Whh, wf8D, bid * 256 + tid); return; }
    bid -= 32;
    if (bid < 16) { do_packfrag(er_W1, w1f, bid * 256 + tid, 8, 0); return; }
    bid -= 16;
    if (bid < 520) { do_cvt(rr_W, rwbf, bid * 256 + tid, 256, 516, 516, 0, 520); return; }
    bid -= 520;
    if (bid < 768) { do_cvt(upd_Wih, uwbf, bid * 256 + tid, 768, 256, 256, 0, 256); return; }
    bid -= 768;
    if (bid < 768) { do_cvt(dec_Wih, dwbf, bid * 256 + tid, 768, 256, 256, 0, 256); return; }
    bid -= 768;
    if (bid < 256) { do_cvt(er_W0, w0bf, bid * 256 + tid, 256, 256, 512, 0, 256); return; }
    bid -= 256;
    if (bid < 256) { do_cvt(er_W0, w0bf + 256 * 256, bid * 256 + tid, 256, 256, 512, 256, 256); return; }
    bid -= 256;
    do_c0(z_ph, init_ph, cc_W0, cc_b0, cc_W1, cc_b1, cc_W2, cc_b2,
          c0_out, out_zero, tid);
}

// ---------------------------------------------------------------------------
// K3: bf16 MFMA GEMM, 64x64 tile, K chunked by 128, XOR-swizzled LDS.
// ---------------------------------------------------------------------------
__global__ __launch_bounds__(256) void gemm_mfma(
    const float* __restrict__ A, const unsigned short* __restrict__ B,
    const float* __restrict__ bias, const float* __restrict__ c0,
    float* __restrict__ C, float* __restrict__ C2,
    int M, int N, int K, int lda, int ldb, int mode, int act, int split)
{
    __shared__ __align__(16) unsigned short As[64 * 128];
    __shared__ __align__(16) unsigned short Bs[64 * 128];
    const int tid = threadIdx.x;
    const int m0 = blockIdx.x * 64, n0 = blockIdx.y * 64;
    const int wave = tid >> 6, lane = tid & 63;
    const int lr = lane & 15, quad = lane >> 4;

    v4f acc[4];
    const v4f z4 = {0.f, 0.f, 0.f, 0.f};
#pragma unroll
    for (int nt = 0; nt < 4; ++nt) acc[nt] = z4;

    for (int k0 = 0; k0 < K; k0 += 128) {
        for (int idx = tid; idx < 64 * 32; idx += 256) {
            int r = idx >> 5, kq = idx & 31;
            int k = k0 + kq * 4;
            int m = m0 + r; if (m > M - 1) m = M - 1;
            float4 a = {0.f, 0.f, 0.f, 0.f};
            if (k < K) {
                const float* Ar;
                if (mode == 1) {
                    int ss = m / 127, tt = m - ss * 127;
                    Ar = A + (size_t)(ss * 128 + tt + 1) * lda;
                } else if (mode == 2) {
                    int tt = m % 127;
                    Ar = (tt == 0) ? c0 : (A + (size_t)(m - 1) * lda);
                } else {
                    Ar = A + (size_t)m * lda;
                }
                a = *(const float4*)&Ar[k];
            }
            store4bf(&As[r * 128 + (((kq >> 1) ^ (r & 7)) << 3) + ((kq & 1) << 2)], a);
        }
        for (int idx = tid; idx < 64 * 16; idx += 256) {
            int c = idx >> 4, kb = idx & 15;
            int k = k0 + kb * 8;
            int n = n0 + c;
            uint4 bv = {0u, 0u, 0u, 0u};
            if (k < K) bv = *(const uint4*)&B[(size_t)n * ldb + k];
            *(uint4*)&Bs[c * 128 + ((kb ^ (c & 7)) << 3)] = bv;
        }
        __syncthreads();
        const int row = wave * 16 + lr;
        const int rem = K - k0;
        const int kkm = (rem >= 128) ? 4 : ((rem + 31) >> 5);
        for (int kk = 0; kk < kkm; ++kk) {
            const v8bf af = *(const v8bf*)&As[row * 128 + ((((kk << 2) + quad) ^ (row & 7)) << 3)];
#pragma unroll
            for (int nt = 0; nt < 4; ++nt) {
                const int col = nt * 16 + lr;
                const v8bf bf = *(const v8bf*)&Bs[col * 128 + ((((kk << 2) + quad) ^ (col & 7)) << 3)];
                acc[nt] = __builtin_amdgcn_mfma_f32_16x16x32_bf16(af, bf, acc[nt], 0, 0, 0);
            }
        }
        __syncthreads();
    }
#pragma unroll
    for (int nt = 0; nt < 4; ++nt) {
        const int col = n0 + nt * 16 + lr;
#pragma unroll
        for (int r = 0; r < 4; ++r) {
            const int row = m0 + wave * 16 + quad * 4 + r;
            if (row < M) {
                float v = acc[nt][r];
                if (split) {
                    if (col < 256)
                        ((unsigned short*)C)[(size_t)row * 256 + col] = f2bf(v);
                    else
                        ((unsigned short*)C2)[(size_t)row * 256 + (col - 256)] =
                            f2bf(v + bias[col - 256]);
                } else {
                    if (bias) v += bias[col];
                    if (act) v = fmaxf(v, 0.f);
                    C[(size_t)row * N + col] = v;
                }
            }
        }
    }
}

// ---------------------------------------------------------------------------
// K4: GRU scan v9 — MFMA matvec, mixed-precision streamed weights.
// 512 thr/sample. Per wave: r tiles {2w,2w+1} + z tiles {16+2w,16+2w+1} in
// FP8 (streamed as uint4 frag-pairs, 8 KB/tile -> 4 KB/tile) and n tiles
// {2w,2w+1} in BF16. Streamed bytes/step: 256 KB (vs 384 all-bf16) — the
// per-CU L1-fill ceiling (~131 B/cyc) is the binding constraint.
// h kept fp32 for recurrence; packed to bf16 AND fp8 per step for A-frags.
// ---------------------------------------------------------------------------
__global__ __launch_bounds__(512, 2) void gru_scan9(
    const float* __restrict__ gi, const uint4* __restrict__ wfn,
    const uint4* __restrict__ wf8,
    const float* __restrict__ bhh, float* __restrict__ outp, int T)
{
    const int s = blockIdx.x, tid = threadIdx.x;
    const int w = tid >> 6, lane = tid & 63;
    const int quad = lane >> 4;
    __shared__ unsigned int hbuf[2][128];   // bf16 pairs
    __shared__ unsigned int hbuf8[2][64];   // fp8 quads
    __shared__ float dred[768];

    // streamed pointers (lane-fixed)
    const uint4* pr = wf8 + (size_t)((2 * w) * 4) * 64 + lane;        // r tiles 2w,2w+1
    const uint4* pz = wf8 + (size_t)((16 + 2 * w) * 4) * 64 + lane;   // z tiles
    const uint4* pn = wfn + (size_t)((2 * w) * 8) * 64 + lane;        // n tiles (bf16)

    float br = 0.f, bz = 0.f, bn = 0.f;
    float g_r = 0.f, g_z = 0.f, g_n = 0.f;
    const float* g0 = gi + (size_t)s * T * G_;
    float* o0 = outp + (size_t)s * T * D_;
    float h = 0.f;
    if (tid < 256) {
        br = bhh[tid]; bz = bhh[256 + tid]; bn = bhh[512 + tid];
        g_r = g0[tid]; g_z = g0[256 + tid]; g_n = g0[512 + tid];
    }
    if (tid < 128) { hbuf[0][tid] = 0u; hbuf[1][tid] = 0u; }
    if (tid < 64) { hbuf8[0][tid] = 0u; hbuf8[1][tid] = 0u; }

    v4f acc[6];
    const v4f z4 = {0.f, 0.f, 0.f, 0.f};
#pragma unroll
    for (int c = 0; c < 6; ++c) acc[c] = z4;
    __syncthreads();

    for (int t = 0; t < T; ++t) {
        float ngr = 0.f, ngz = 0.f, ngn = 0.f;
        if (tid < 256 && t + 1 < T) {
            const float* gn_ = g0 + (size_t)(t + 1) * G_;
            ngr = gn_[tid]; ngz = gn_[256 + tid]; ngn = gn_[512 + tid];
        }
        const unsigned int* hq = hbuf[t & 1];
        const unsigned int* hq8 = hbuf8[t & 1];
        // A-fragments (bf16 for n, fp8 for r/z)
        v8bf afb[8];
#pragma unroll
        for (int kk = 0; kk < 8; ++kk)
            afb[kk] = *(const v8bf*)&hq[kk * 16 + quad * 4];
        uint2 af8[8];
#pragma unroll
        for (int kk = 0; kk < 8; ++kk)
            af8[kk] = *(const uint2*)&hq8[kk * 8 + quad * 2];

        // r tiles (fp8): acc0, acc1
#pragma unroll
        for (int c2 = 0; c2 < 2; ++c2) {
            v4f a = acc[c2];
#pragma unroll
            for (int kp = 0; kp < 4; ++kp) {
                uint4 q = pr[(c2 * 4 + kp) << 6];
                a = mfma_fp8(af8[2 * kp], q.x, q.y, a);
                a = mfma_fp8(af8[2 * kp + 1], q.z, q.w, a);
            }
            acc[c2] = a;
        }
        // z tiles (fp8): acc2, acc3
#pragma unroll
        for (int c2 = 0; c2 < 2; ++c2) {
            v4f a = acc[2 + c2];
#pragma unroll
            for (int kp = 0; kp < 4; ++kp) {
                uint4 q = pz[(c2 * 4 + kp) << 6];
                a = mfma_fp8(af8[2 * kp], q.x, q.y, a);
                a = mfma_fp8(af8[2 * kp + 1], q.z, q.w, a);
            }
            acc[2 + c2] = a;
        }
        // n tiles (bf16): acc4, acc5
#pragma unroll
        for (int c2 = 0; c2 < 2; ++c2) {
            v4f a = acc[4 + c2];
#pragma unroll
            for (int kk = 0; kk < 8; ++kk) {
                uint4 q = pn[(c2 * 8 + kk) << 6];
                a = __builtin_amdgcn_mfma_f32_16x16x32_bf16(afb[kk], u4_to_v8bf(q), a, 0, 0, 0);
            }
            acc[4 + c2] = a;
        }

        // y extraction: D row 0 = lanes 0..15, reg 0
        if (lane < 16) {
            dred[32 * w + lane]            = acc[0][0];
            dred[32 * w + 16 + lane]       = acc[1][0];
            dred[256 + 32 * w + lane]      = acc[2][0];
            dred[256 + 32 * w + 16 + lane] = acc[3][0];
            dred[512 + 32 * w + lane]      = acc[4][0];
            dred[512 + 32 * w + 16 + lane] = acc[5][0];
        }
#pragma unroll
        for (int c = 0; c < 6; ++c) acc[c] = z4;
        __syncthreads();
        if (tid < 256) {
            const float rg = sigmoidf_(g_r + dred[tid] + br);
            const float zg = sigmoidf_(g_z + dred[256 + tid] + bz);
            const float ng = fast_tanh(g_n + rg * (dred[512 + tid] + bn));
            const float hnew = ng + zg * (h - ng);
            h = hnew;
            o0[(size_t)t * D_ + tid] = hnew;
            // bf16 pack (pairs)
            const float ho = __shfl_xor(hnew, 1);
            if ((tid & 1) == 0)
                hbuf[(t + 1) & 1][tid >> 1] =
                    (unsigned int)f2bf(hnew) | ((unsigned int)f2bf(ho) << 16);
            // fp8 pack (quads)
            unsigned int b0 = f2fp8(hnew);
            unsigned int b1 = __shfl_down(b0, 1);
            unsigned int b2 = __shfl_down(b0, 2);
            unsigned int b3 = __shfl_down(b0, 3);
            if ((tid & 3) == 0)
                hbuf8[(t + 1) & 1][tid >> 2] = b0 | (b1 << 8) | (b2 << 16) | (b3 << 24);
            g_r = ngr; g_z = ngz; g_n = ngn;
        }
        __syncthreads();
    }
}

// ---------------------------------------------------------------------------
// K5: edge readout v2 (unchanged).
// ---------------------------------------------------------------------------
__global__ __launch_bounds__(256, 3) void edge_kernel2(
    const unsigned short* __restrict__ Abf, const unsigned short* __restrict__ Bbf,
    const uint4* __restrict__ w1f, const float* __restrict__ b1,
    const float* __restrict__ W2, const float* __restrict__ b2,
    const float* __restrict__ con, float* __restrict__ out)
{
    __shared__ __align__(16) unsigned short h1s[64 * 256];
    __shared__ int ijs[128];
    __shared__ float part[4][64][2];
    const int tid = threadIdx.x;
    const int s = blockIdx.y;
    const int e0 = blockIdx.x * 64;
    const int wave = tid >> 6, lane = tid & 63;
    const int lr = lane & 15, quad = lane >> 4;

    uint4 wfr[2][8];
#pragma unroll
    for (int c = 0; c < 2; ++c)
#pragma unroll
        for (int kk = 0; kk < 8; ++kk)
            wfr[c][kk] = w1f[((((wave * 2 + c) * 8) + kk) << 6) | lane];

    const int ca = wave * 32 + lr, cb = wave * 32 + 16 + lr;
    const float b1a = b1[ca], b1b = b1[cb];
    const float w20a = W2[ca], w20b = W2[cb];
    const float w21a = W2[128 + ca], w21b = W2[128 + cb];
    const float cb20 = b2[0], cb21 = b2[1];

    if (tid < 64) {
        int e = e0 + tid;
        int i = (int)((sqrtf(8.f * (float)e + 1.f) - 1.f) * 0.5f);
        while (((i + 1) * (i + 2)) / 2 <= e) ++i;
        while ((i * (i + 1)) / 2 > e) --i;
        ijs[tid * 2] = i;
        ijs[tid * 2 + 1] = e - (i * (i + 1)) / 2;
    }
    __syncthreads();

    {
        const unsigned short* Aro = Abf + (size_t)s * NM1 * 256;
        const unsigned short* Bro = Bbf + (size_t)s * NM1 * 256;
#pragma unroll
        for (int it = 0; it < 8; ++it) {
            int idx = tid + it * 256;
            int e = idx >> 5, k8 = idx & 31;
            int i = ijs[2 * e], j = ijs[2 * e + 1];
            uint4 av = *(const uint4*)&Aro[(size_t)j * 256 + k8 * 8];
            uint4 bv = *(const uint4*)&Bro[(size_t)i * 256 + k8 * 8];
            unsigned int rr[4];
#pragma unroll
            for (int wd = 0; wd < 4; ++wd) {
                unsigned int aw = (&av.x)[wd], bw = (&bv.x)[wd];
                float lo = fmaxf(bflo(aw) + bflo(bw), 0.f);
                float hi = fmaxf(bfhi(aw) + bfhi(bw), 0.f);
                rr[wd] = (unsigned int)f2bf(lo) | ((unsigned int)f2bf(hi) << 16);
            }
            uint4 hv; hv.x = rr[0]; hv.y = rr[1]; hv.z = rr[2]; hv.w = rr[3];
            *(uint4*)&h1s[e * 256 + ((k8 ^ (e & 7)) << 3)] = hv;
        }
    }
    __syncthreads();

    v4f acc[4][2];
    const v4f z4 = {0.f, 0.f, 0.f, 0.f};
#pragma unroll
    for (int rt = 0; rt < 4; ++rt) { acc[rt][0] = z4; acc[rt][1] = z4; }

#pragma unroll
    for (int kk = 0; kk < 8; ++kk) {
        v8bf af[4];
#pragma unroll
        for (int rt = 0; rt < 4; ++rt) {
            const int row = rt * 16 + lr;
            af[rt] = *(const v8bf*)&h1s[row * 256 + ((((kk << 2) + quad) ^ (row & 7)) << 3)];
        }
#pragma unroll
        for (int rt = 0; rt < 4; ++rt) {
            acc[rt][0] = __builtin_amdgcn_mfma_f32_16x16x32_bf16(
                af[rt], u4_to_v8bf(wfr[0][kk]), acc[rt][0], 0, 0, 0);
            acc[rt][1] = __builtin_amdgcn_mfma_f32_16x16x32_bf16(
                af[rt], u4_to_v8bf(wfr[1][kk]), acc[rt][1], 0, 0, 0);
        }
    }

#pragma unroll
    for (int rt = 0; rt < 4; ++rt) {
#pragma unroll
        for (int r = 0; r < 4; ++r) {
            float h2a = fmaxf(acc[rt][0][r] + b1a, 0.f);
            float h2b = fmaxf(acc[rt][1][r] + b1b, 0.f);
            float p0 = h2a * w20a + h2b * w20b;
            float p1 = h2a * w21a + h2b * w21b;
#pragma unroll
            for (int d = 1; d < 16; d <<= 1) {
                p0 += __shfl_xor(p0, d);
                p1 += __shfl_xor(p1, d);
            }
            if (lr == 0) {
                int e = rt * 16 + quad * 4 + r;
                part[wave][e][0] = p0;
                part[wave][e][1] = p1;
            }
        }
    }
    __syncthreads();

    if (tid < 64) {
        float l0 = part[0][tid][0] + part[1][tid][0] + part[2][tid][0] + part[3][tid][0] + cb20;
        float l1 = part[0][tid][1] + part[1][tid][1] + part[2][tid][1] + part[3][tid][1] + cb21;
        int e = e0 + tid;
        float mx = fmaxf(l0, l1);
        float lse = mx + logf(__expf(l0 - mx) + __expf(l1 - mx));
        float lp0 = fmaxf(l0 - lse, -100.f);
        float lp1 = fmaxf(l1 - lse, -100.f);
        float c0v = con[((size_t)s * TRI_ + e) * 2];
        float c1v = con[((size_t)s * TRI_ + e) * 2 + 1];
        float bsum0 = -(c0v * lp0 + (1.f - c0v) * lp1);
        float bsum1 = -(c1v * lp1 + (1.f - c1v) * lp0);
#pragma unroll
        for (int d = 1; d < 64; d <<= 1) {
            bsum0 += __shfl_xor(bsum0, d);
            bsum1 += __shfl_xor(bsum1, d);
        }
        if (tid == 0) {
            atomicAdd(&out[s * 2], bsum0);
            atomicAdd(&out[s * 2 + 1], bsum1);
        }
    }
}

// ---------------------------------------------------------------------------
extern "C" void kernel_launch(void* const* d_in, const int* in_sizes, int n_in,
                              void* d_out, int out_size, void* d_ws, size_t ws_size,
                              hipStream_t stream)
{
    (void)in_sizes; (void)n_in; (void)out_size; (void)ws_size;
    const float* x        = (const float*)d_in[0];
    const float* con      = (const float*)d_in[1];
    const float* z_ph     = (const float*)d_in[2];
    const float* init_ph  = (const float*)d_in[3];
    const float* cc_W0    = (const float*)d_in[4];
    const float* cc_b0    = (const float*)d_in[5];
    const float* cc_W1    = (const float*)d_in[6];
    const float* cc_b1    = (const float*)d_in[7];
    const float* cc_W2    = (const float*)d_in[8];
    const float* cc_b2    = (const float*)d_in[9];
    const float* er_W0    = (const float*)d_in[10];
    const float* er_b0    = (const float*)d_in[11];
    const float* er_W1    = (const float*)d_in[12];
    const float* er_b1    = (const float*)d_in[13];
    const float* er_W2    = (const float*)d_in[14];
    const float* er_b2    = (const float*)d_in[15];
    const float* rr_W     = (const float*)d_in[16];
    const float* rr_b     = (const float*)d_in[17];
    const float* dec_Wih  = (const float*)d_in[18];
    const float* dec_Whh  = (const float*)d_in[19];
    const float* dec_bih  = (const float*)d_in[20];
    const float* dec_bhh  = (const float*)d_in[21];
    const float* upd_Wih  = (const float*)d_in[22];
    const float* upd_Whh  = (const float*)d_in[23];
    const float* upd_bih  = (const float*)d_in[24];
    const float* upd_bhh  = (const float*)d_in[25];
    float* out = (float*)d_out;

    float* ws = (float*)d_ws;
    float* c0v  = ws;                               // 256
    float* gi   = ws + 256;                         // M_*G_
    float* bufA = gi + (size_t)M_ * G_;             // M_*D_ (rnninp fp32, Amat bf16)
    float* bufB = bufA + (size_t)M_ * D_;           // M_*D_ (u_out fp32, Bmat bf16)
    float* memb = bufB + (size_t)M_ * D_;           // M_*D_ (mem fp32)
    unsigned short* rwbf = (unsigned short*)(memb + (size_t)M_ * D_); // 256*520
    unsigned short* uwbf = rwbf + 256 * 520;                          // 768*256
    unsigned short* dwbf = uwbf + 768 * 256;                          // 768*256
    unsigned short* w0bf = dwbf + 768 * 256;                          // 512*256
    uint4* wfnU = (uint4*)(((size_t)(w0bf + 512 * 256) + 15) & ~(size_t)15); // 16*8*64
    uint4* wfnD = wfnU + 16 * 8 * 64;                                 // 16*8*64
    uint4* wf8U = wfnD + 16 * 8 * 64;                                 // 32*4*64
    uint4* wf8D = wf8U + 32 * 4 * 64;                                 // 32*4*64
    uint4* w1f  = wf8D + 32 * 4 * 64;                                 // 8*8*64

    // 1) fused weight prep + c0 + out-zero
    prep_all<<<PREP_BLOCKS, 256, 0, stream>>>(upd_Whh, wfnU, wf8U,
                                              dec_Whh, wfnD, wf8D,
                                              er_W1, w1f,
                                              rr_W, rwbf, upd_Wih, uwbf,
                                              dec_Wih, dwbf, er_W0, w0bf,
                                              z_ph, init_ph, cc_W0, cc_b0,
                                              cc_W1, cc_b1, cc_W2, cc_b2,
                                              c0v, out);
    // 2) rnninp = relu(x[:,1:] @ rr_W.T + rr_b)   -> bufA
    gemm_mfma<<<dim3((M_ + 63) / 64, 256 / 64), 256, 0, stream>>>(
        x, rwbf, rr_b, nullptr, bufA, nullptr, M_, 256, 516, 516, 520, 1, 1, 0);
    // 3) gi_u = rnninp @ upd_Wih.T + upd_bih      -> gi
    gemm_mfma<<<dim3((M_ + 63) / 64, 768 / 64), 256, 0, stream>>>(
        bufA, uwbf, upd_bih, nullptr, gi, nullptr, M_, 768, 256, 256, 256, 0, 0, 0);
    // 4) u_out = GRU(gi_u; upd)                   -> bufB
    gru_scan9<<<S_, 512, 0, stream>>>(gi, wfnU, wf8U, upd_bhh, bufB, NM1);
    // 5) gi_d = content_seq @ dec_Wih.T + dec_bih -> gi
    gemm_mfma<<<dim3((M_ + 63) / 64, 768 / 64), 256, 0, stream>>>(
        bufB, dwbf, dec_bih, c0v, gi, nullptr, M_, 768, 256, 256, 256, 2, 0, 0);
    // 6) mem = GRU(gi_d; dec)                     -> memb
    gru_scan9<<<S_, 512, 0, stream>>>(gi, wfnD, wf8D, dec_bhh, memb, NM1);
    // 7+8) Amat / Bmat = mem @ er_W0 halves (split N=512, bf16 out)
    gemm_mfma<<<dim3((M_ + 63) / 64, 512 / 64), 256, 0, stream>>>(
        memb, w0bf, er_b0, nullptr, bufA, bufB, M_, 512, 256, 256, 256, 0, 0, 1);
    // 9) fused edge readout -> out (atomicAdd)
    edge_kernel2<<<dim3(TRI_ / 64, S_), 256, 0, stream>>>(
        (const unsigned short*)bufA, (const unsigned short*)bufB,
        w1f, er_b1, er_W2, er_b2, con, out);
}